// Round 19
// baseline (198.145 us; speedup 1.0000x reference)
//
#include <hip/hip_runtime.h>

// Problem constants (match reference)
#define K_     1056
#define N_     2112
#define M_     1056   // N - K
#define E_     6336   // M * 6
#define NIE_   5280   // M * 5 info-side edges (c2v state, CN-major: m*5+j)
#define IDXCAP_ 6336  // u16 index-CSR extent (stride = d|1 pads <= K)
#define DV_    5
#define ROW_   6      // edge 6m+5 is the parity VN K+m
#define NSYM_  528
#define NITER_ 20
#define BATCH_ 1024
#define BS_    512    // 8 waves/block -> 4 blocks/CU fills all 32 wave slots

#define LOG2E_ 1.4426950408889634f
#define AVLO_  (1e-6f * LOG2E_)          // |v2c| floor, bits units
#define AVHI_  (20.0f * LOG2E_)          // |v2c| cap,  bits units
#define QC_    0.99999988f               // tanh-domain cap (unchanged)

// stride(d) = d | 1 : always ODD -> coprime with 32 banks.
__device__ __forceinline__ int seg_stride(int d) { return d | 1; }

// Bare-instruction transcendentals (R17 win: OCML wrappers inflated the
// hot loop ~2x; inputs always normal-range, <=1 ULP deviation validated).
__device__ __forceinline__ float fexp2(float x) { return __builtin_amdgcn_exp2f(x); }
__device__ __forceinline__ float flog2(float x) { return __builtin_amdgcn_logf(x); }
__device__ __forceinline__ float frcp(float x)  { return __builtin_amdgcn_rcpf(x); }

// -------------------------------------------------------------------------
// Single kernel, one block per codeword, 512 threads / 8 waves.
//
// R18: CN-MAJOR message layout. R13-R17 spilled ~14 dwords/thread of
// per-edge index registers (vnp) to L2 scratch at the (512,8) 32-arch-VGPR
// split — reloaded every iteration (WRITE 37 MB, FETCH 15 MB, latency in
// the 30% idle). Now:
//   * c2v[m*5+j] — Phase B address is arithmetic, NO index registers;
//     lane stride 5 (odd) -> conflict-free read AND write.
//   * Phase A gathers via s_idx (u16 CSR in LDS, odd-stride segments) —
//     indices moved from registers to LDS.
//   * Phase B's marg slots: 5 x u16 packed in 3 u32/check (9 persistents).
// Float math, accumulation order, clamps: byte-identical to R17.
//
// LDS (~38.5 KB, 4 blocks/CU):
//   s_c2v[NIE]   messages (staging + build int scratch before BP)
//   s_marg[K]    slot-indexed marginals (build: edge-fill cursors)
//   s_idx[IDXCAP] u16 VN-major CSR of CN-major positions
//
// Structure: H = [A | I]; parity VN deg-1 -> per-check constant t5;
// degree-sorted slots (wave-uniform Phase A trips); scan-free bases from
// 32-bin histogram; atomic build order only permutes accumulation order
// (validated order-independent R4-R17, absmax 0).
// -------------------------------------------------------------------------
__global__ __launch_bounds__(BS_, 8) void link_kernel(
    const int*   __restrict__ bits,      // [B,K]
    const int*   __restrict__ a_idx,     // [M,DV]
    const float* __restrict__ points_re, // [16]
    const float* __restrict__ points_im, // [16]
    const float* __restrict__ noise_re,  // [B,NSYM]
    const float* __restrict__ noise_im,  // [B,NSYM]
    const float* __restrict__ ebno_db,   // [1]
    const int*   __restrict__ edge_vn,   // [E]
    float*       __restrict__ out)       // [2,B,K]
{
#pragma clang fp contract(off)
    const int b   = blockIdx.x;
    const int tid = threadIdx.x;

    __shared__ float s_c2v[NIE_];
    __shared__ float s_marg[K_];
    __shared__ unsigned short s_idx[IDXCAP_];
    __shared__ float s_pre[16];
    __shared__ float s_pim[16];
    __shared__ int   s_hist[32];
    __shared__ int   s_binStart[32];
    __shared__ int   s_binBase[32];

    // build scratch: tail of s_c2v ([N..NIE) = 3168 ints, exact fit for 3*K)
    int* sc_tail   = (int*)s_c2v + N_;
    int* s_deg     = sc_tail;            // [K]
    int* s_perm    = sc_tail + K_;       // [K] slot -> v | deg<<16
    int* s_offslot = sc_tail + 2 * K_;   // [K] v -> idxbase | slot<<16
    int* s_cnt     = (int*)s_marg;       // [K] edge-fill cursors

    if (tid < 16) {
        s_pre[tid] = points_re[tid];
        s_pim[tid] = points_im[tid];
    }
    if (tid < 32) s_hist[tid] = 0;

    const float eb    = ebno_db[0];
    const float no    = 1.0f / ((powf(10.0f, eb / 10.0f) * 0.5f) * 4.0f);
    const float sigma = sqrtf(no / 2.0f);

    // ---- stage info bits (0/1 floats); output0 = bits.astype(f32) ----
    for (int i = tid; i < K_; i += BS_) {
        int v = bits[b * K_ + i];
        s_c2v[i] = (float)v;
        out[b * K_ + i] = (float)v;
    }
    __syncthreads();

    // ---- parity: XOR of DV gathered info bits; zero build counters ----
    for (int m = tid; m < M_; m += BS_) {
        float acc = 0.0f;
        #pragma unroll
        for (int d = 0; d < DV_; ++d) acc += s_c2v[a_idx[m * DV_ + d]];
        s_c2v[K_ + m] = (float)(((int)acc) & 1);
    }
    for (int v = tid; v < K_; v += BS_) { s_deg[v] = 0; s_cnt[v] = 0; }
    __syncthreads();

    // ---- QAM + AWGN + exact APP demap, two-pass streaming (in staging) ----
    // ---- overlapped: VN degree count (disjoint LDS region)             ----
    for (int s = tid; s < NSYM_; s += BS_) {
        int c0 = (int)s_c2v[4 * s + 0];
        int c1 = (int)s_c2v[4 * s + 1];
        int c2 = (int)s_c2v[4 * s + 2];
        int c3 = (int)s_c2v[4 * s + 3];
        int sym = c0 * 8 + c1 * 4 + c2 * 2 + c3;
        float yre = s_pre[sym] + sigma * noise_re[b * NSYM_ + s];
        float yim = s_pim[sym] + sigma * noise_im[b * NSYM_ + s];
        float m0[4], m1[4];
        #pragma unroll
        for (int j = 0; j < 4; ++j) { m0[j] = -1e30f; m1[j] = -1e30f; }
        #pragma unroll
        for (int p = 0; p < 16; ++p) {
            float dre  = yre - s_pre[p];
            float dim_ = yim - s_pim[p];
            float lg   = -(dre * dre + dim_ * dim_) / no;
            #pragma unroll
            for (int j = 0; j < 4; ++j) {
                if (((p >> (3 - j)) & 1) == 0) m0[j] = fmaxf(m0[j], lg);
                else                           m1[j] = fmaxf(m1[j], lg);
            }
        }
        float sum0[4] = {0.0f, 0.0f, 0.0f, 0.0f};
        float sum1[4] = {0.0f, 0.0f, 0.0f, 0.0f};
        #pragma unroll
        for (int p = 0; p < 16; ++p) {
            float dre  = yre - s_pre[p];
            float dim_ = yim - s_pim[p];
            float lg   = -(dre * dre + dim_ * dim_) / no;
            #pragma unroll
            for (int j = 0; j < 4; ++j) {
                if (((p >> (3 - j)) & 1) == 0) sum0[j] += __expf(lg - m0[j]);
                else                           sum1[j] += __expf(lg - m1[j]);
            }
        }
        #pragma unroll
        for (int j = 0; j < 4; ++j) {
            float llr = (m0[j] + __logf(sum0[j])) - (m1[j] + __logf(sum1[j]));
            s_c2v[4 * s + j] = llr * LOG2E_;
        }
    }
    for (int idx = tid; idx < NIE_; idx += BS_) {
        int m = idx / 5, j = idx - m * 5;
        atomicAdd(&s_deg[edge_vn[m * ROW_ + j]], 1);
    }
    __syncthreads();

    // ---- degree histogram -> arithmetic segment bases (scan-free) ----
    for (int v = tid; v < K_; v += BS_) atomicAdd(&s_hist[s_deg[v] & 31], 1);
    __syncthreads();
    if (tid == 0) {
        int accS = 0, accB = 0;
        for (int d = 0; d < 32; ++d) {
            int c = s_hist[d];
            s_binStart[d] = accS;
            s_binBase[d]  = accB;
            s_hist[d]     = accS;        // reuse as sort cursor
            accS += c;
            accB += c * seg_stride(d);
        }
    }
    __syncthreads();
    for (int v = tid; v < K_; v += BS_) {   // counting sort by degree
        int d    = s_deg[v];
        int slot = atomicAdd(&s_hist[d & 31], 1);
        int base = s_binBase[d] + (slot - s_binStart[d]) * seg_stride(d);
        s_perm[slot]  = v | (d << 16);
        s_offslot[v]  = base | (slot << 16);
    }
    __syncthreads();

    // ---- capture iteration-invariant state + fill index CSR ----
    int      pv[3];                      // slot -> VN id
    unsigned od[3];                      // idxbase | deg<<16
    float    lr[3];                      // channel LLR_hat of owned VN
    #pragma unroll
    for (int k = 0; k < 3; ++k) {
        int s = tid + BS_ * k;
        if (s < K_) {
            int w = s_perm[s];
            int v = w & 0xFFFF;
            int d = w >> 16;
            int base = s_binBase[d] + (s - s_binStart[d]) * seg_stride(d);
            pv[k] = v;
            od[k] = (unsigned)base | ((unsigned)d << 16);
            lr[k] = s_c2v[v];            // staging still intact
        } else { pv[k] = 0; od[k] = 0; lr[k] = 0.0f; }
    }
    float    t5[3];
    unsigned sp0[3], sp1[3], sp2[3];     // 5 marg slots packed per check
    #pragma unroll
    for (int kk = 0; kk < 3; ++kk) {
        int m = tid + BS_ * kk;
        if (m < M_) {
            unsigned sl[5];
            #pragma unroll
            for (int j = 0; j < 5; ++j)
                sl[j] = (unsigned)(s_offslot[edge_vn[m * ROW_ + j]] >> 16);
            sp0[kk] = sl[0] | (sl[1] << 16);
            sp1[kk] = sl[2] | (sl[3] << 16);
            sp2[kk] = sl[4];
            float lrP = s_c2v[K_ + m];   // parity channel LLR (staging)
            float av  = __builtin_amdgcn_fmed3f(fabsf(lrP), AVLO_, AVHI_);
            float e   = fexp2(-av);
            float tm  = (1.0f - e) * frcp(1.0f + e);
            t5[kk] = copysignf(tm, lrP);
        } else { t5[kk] = 0.0f; sp0[kk] = sp1[kk] = sp2[kk] = 0u; }
    }
    // index CSR fill (reads s_offslot/s_cnt; writes s_idx only)
    for (int idx = tid; idx < NIE_; idx += BS_) {
        int m = idx / 5, j = idx - m * 5;
        int v = edge_vn[m * ROW_ + j];
        int r = atomicAdd(&s_cnt[v], 1);
        int w = s_offslot[v];
        s_idx[(w & 0xFFFF) + r] = (unsigned short)(m * 5 + j);
    }
    __syncthreads();
    // scratch + staging fully consumed -> zero the message array
    for (int i = tid; i < NIE_; i += BS_) s_c2v[i] = 0.0f;
    __syncthreads();

    // ---- sum-product BP, flooding (bits domain) ----
    for (int it = 0; it < NITER_; ++it) {
        // Phase A: marginals via index CSR (odd-stride index segments;
        // value gathers random ~2-way = free per CDNA LDS rules)
        #pragma unroll
        for (int k = 0; k < 3; ++k) {
            int s = tid + BS_ * k;
            if (s < K_) {
                int base = (int)(od[k] & 0xFFFFu);
                int dg   = (int)(od[k] >> 16);
                float mg = lr[k];
                int d = 0;
                for (; d + 1 < dg; d += 2) {
                    int p0 = s_idx[base + d];
                    int p1 = s_idx[base + d + 1];
                    mg += s_c2v[p0];
                    mg += s_c2v[p1];
                }
                if (d < dg) mg += s_c2v[s_idx[base + d]];
                s_marg[s] = mg;
            }
        }
        __syncthreads();
        // Phase B: CN update; c2v address = m*5+j (stride-5 conflict-free);
        // old c2v re-read from LDS (own value); bare transcendentals
        #pragma unroll
        for (int kk = 0; kk < 3; ++kk) {
            int m = tid + BS_ * kk;
            if (m < M_) {
                int eb5 = m * 5;
                int sl[5];
                sl[0] = (int)(sp0[kk] & 0xFFFFu);
                sl[1] = (int)(sp0[kk] >> 16);
                sl[2] = (int)(sp1[kk] & 0xFFFFu);
                sl[3] = (int)(sp1[kk] >> 16);
                sl[4] = (int)sp2[kk];
                float tj[5];
                #pragma unroll
                for (int j = 0; j < 5; ++j) {
                    float v2c = s_marg[sl[j]] - s_c2v[eb5 + j];
                    float av  = __builtin_amdgcn_fmed3f(fabsf(v2c), AVLO_, AVHI_);
                    float e   = fexp2(-av);
                    float tm  = (1.0f - e) * frcp(1.0f + e);
                    tj[j] = copysignf(tm, v2c);
                }
                float qv[5];
                float pr = t5[kk];
                #pragma unroll
                for (int j = 0; j < 5; ++j) { qv[j] = pr; pr *= tj[j]; }
                float sf = 1.0f;
                #pragma unroll
                for (int j = 4; j >= 0; --j) { qv[j] *= sf; sf *= tj[j]; }
                #pragma unroll
                for (int j = 0; j < 5; ++j) {
                    float q = __builtin_amdgcn_fmed3f(qv[j], -QC_, QC_);
                    float r = flog2((1.0f + q) * frcp(1.0f - q));
                    s_c2v[eb5 + j] = r;
                }
            }
        }
        __syncthreads();
    }

    // ---- final marginal + hard decision on info VNs ----
    #pragma unroll
    for (int k = 0; k < 3; ++k) {
        int s = tid + BS_ * k;
        if (s < K_) {
            int base = (int)(od[k] & 0xFFFFu);
            int dg   = (int)(od[k] >> 16);
            float mg = lr[k];
            int d = 0;
            for (; d + 1 < dg; d += 2) {
                int p0 = s_idx[base + d];
                int p1 = s_idx[base + d + 1];
                mg += s_c2v[p0];
                mg += s_c2v[p1];
            }
            if (d < dg) mg += s_c2v[s_idx[base + d]];
            out[(size_t)BATCH_ * K_ + b * K_ + pv[k]] = (mg < 0.0f) ? 1.0f : 0.0f;
        }
    }
}

extern "C" void kernel_launch(void* const* d_in, const int* in_sizes, int n_in,
                              void* d_out, int out_size, void* d_ws, size_t ws_size,
                              hipStream_t stream) {
    const int*   bits    = (const int*)  d_in[0];
    const int*   a_idx   = (const int*)  d_in[1];
    // d_in[2] = edge_cn (implicit: contiguous groups of 6) — unused
    const int*   edge_vn = (const int*)  d_in[3];
    const float* pre     = (const float*)d_in[4];
    const float* pim     = (const float*)d_in[5];
    const float* nre     = (const float*)d_in[6];
    const float* nim     = (const float*)d_in[7];
    const float* ebno    = (const float*)d_in[8];

    link_kernel<<<BATCH_, BS_, 0, stream>>>(bits, a_idx, pre, pim, nre, nim,
                                            ebno, edge_vn, (float*)d_out);
}

// Round 20
// 184.102 us; speedup vs baseline: 1.0763x; 1.0763x over previous
//
#include <hip/hip_runtime.h>

// Problem constants (match reference)
#define K_     1056
#define N_     2112
#define M_     1056   // N - K
#define E_     6336   // M * 6
#define NIE_   5280   // M * 5 info-side edges (the only BP state)
#define CAP_   6336   // padded c2v extent upper bound (stride = d|1 adds <=1/VN)
#define ALL_   7392   // CAP_ + K_ : c2v + marg unified array
#define DV_    5
#define ROW_   6      // edge 6m+5 is the parity VN K+m
#define NSYM_  528
#define NITER_ 20
#define BATCH_ 1024
#define BS_    512    // 8 waves/block -> 4 blocks/CU fills all 32 wave slots

#define LOG2E_ 1.4426950408889634f
#define AVLO_  (1e-6f * LOG2E_)          // |v2c| floor, bits units
#define AVHI_  (20.0f * LOG2E_)          // |v2c| cap,  bits units
#define QC_    0.99999988f               // tanh-domain cap (unchanged)

// stride(d) = d | 1 : always ODD -> coprime with 32 banks -> Phase A's
// wave-uniform-stride segment reads are conflict-free.
__device__ __forceinline__ int seg_stride(int d) { return d | 1; }

// Bare-instruction transcendentals (R17 win: OCML wrappers inflated the
// hot loop ~2x; inputs always normal-range, <=1 ULP deviation validated
// absmax-0 since R1).
__device__ __forceinline__ float fexp2(float x) { return __builtin_amdgcn_exp2f(x); }
__device__ __forceinline__ float flog2(float x) { return __builtin_amdgcn_logf(x); }
__device__ __forceinline__ float frcp(float x)  { return __builtin_amdgcn_rcpf(x); }

// -------------------------------------------------------------------------
// Single kernel, one block per codeword, 512 threads / 8 waves.
// == R17 structure (best: 128 us kernel) + R19 per-bit streaming demap ==
//
// R19: the persistent 37 MB scratch WRITE (invariant R13-R18, 14 dwords/
// thread) is the DEMAP phase: m0[4]+m1[4]+sum0[4]+sum1[4] = 16 live floats
// exceed the 32-arch-VGPR split at (512,8). Per-bit streaming (one j at a
// time: 2-reg max pass, 2-reg sum pass) caps peak live at ~10 regs. lg is
// recomputed with the identical fp sequence; per-j comparison set and
// ascending-p accumulation order unchanged -> bit-identical LLRs.
// R18 lesson: index-CSR gather in Phase A regressed (dependent u16->f32
// LDS chain); sequential float segments restored.
//
// Base-2 LLR domain after demap (LLR_hat = LLR * log2e). LDS ~30 KB:
//   s_all[7392]: build: [0..N) staging, [N..N+4K) int scratch;
//                BP: [0..CAP) c2v odd-stride VN-major segments,
//                    [CAP..) slot-indexed marginals
//
// Structure: H = [A | I]; parity VN deg-1 -> per-check constant t5;
// degree-sorted slots (wave-uniform Phase A trips); scan-free bases from
// 32-bin histogram; atomic build order only permutes accumulation order
// (validated order-independent R4-R18, absmax 0).
//
// CN math (product form, prefix/suffix partial products, bits domain):
//   t = copysign((1-2^-av)/(1+2^-av), v2c);  q_j = t5 * prod_{i!=j} t_i
//   q = med3(q, -QC, QC);  r = log2((1+q)/(1-q))
// -------------------------------------------------------------------------
__global__ __launch_bounds__(BS_, 8) void link_kernel(
    const int*   __restrict__ bits,      // [B,K]
    const int*   __restrict__ a_idx,     // [M,DV]
    const float* __restrict__ points_re, // [16]
    const float* __restrict__ points_im, // [16]
    const float* __restrict__ noise_re,  // [B,NSYM]
    const float* __restrict__ noise_im,  // [B,NSYM]
    const float* __restrict__ ebno_db,   // [1]
    const int*   __restrict__ edge_vn,   // [E]
    float*       __restrict__ out)       // [2,B,K]
{
#pragma clang fp contract(off)
    const int b   = blockIdx.x;
    const int tid = threadIdx.x;

    __shared__ float s_all[ALL_];
    __shared__ float s_pre[16];
    __shared__ float s_pim[16];
    __shared__ int   s_hist[32];
    __shared__ int   s_binStart[32];
    __shared__ int   s_binBase[32];

    float* s_mem  = s_all;               // staging, later c2v [0..CAP)
    float* s_marg = s_all + CAP_;        // BP marginals [CAP..ALL)

    // build scratch aliases [N..N+4K) (inside s_all; demap uses [0..N))
    int* sc        = (int*)(s_all + N_);
    int* s_deg     = sc;                 // [K] degree
    int* s_perm    = sc + K_;            // [K] slot -> v | deg<<16
    int* s_offslot = sc + 2 * K_;        // [K] v -> base | slot<<16
    int* s_cnt     = sc + 3 * K_;        // [K] edge-fill cursors

    if (tid < 16) {
        s_pre[tid] = points_re[tid];
        s_pim[tid] = points_im[tid];
    }
    if (tid < 32) s_hist[tid] = 0;

    const float eb    = ebno_db[0];
    const float no    = 1.0f / ((powf(10.0f, eb / 10.0f) * 0.5f) * 4.0f);
    const float sigma = sqrtf(no / 2.0f);

    // ---- stage info bits (0/1 floats); output0 = bits.astype(f32) ----
    for (int i = tid; i < K_; i += BS_) {
        int v = bits[b * K_ + i];
        s_mem[i] = (float)v;
        out[b * K_ + i] = (float)v;
    }
    __syncthreads();

    // ---- parity: XOR of DV gathered info bits; zero build counters ----
    for (int m = tid; m < M_; m += BS_) {
        float acc = 0.0f;
        #pragma unroll
        for (int d = 0; d < DV_; ++d) acc += s_mem[a_idx[m * DV_ + d]];
        s_mem[K_ + m] = (float)(((int)acc) & 1);
    }
    for (int v = tid; v < K_; v += BS_) { s_deg[v] = 0; s_cnt[v] = 0; }
    __syncthreads();

    // ---- QAM + AWGN + exact APP demap, PER-BIT streaming (R19) ----
    // ---- overlapped: VN degree count (disjoint LDS region)       ----
    for (int s = tid; s < NSYM_; s += BS_) {
        int c0 = (int)s_mem[4 * s + 0];
        int c1 = (int)s_mem[4 * s + 1];
        int c2 = (int)s_mem[4 * s + 2];
        int c3 = (int)s_mem[4 * s + 3];
        int sym = c0 * 8 + c1 * 4 + c2 * 2 + c3;
        float yre = s_pre[sym] + sigma * noise_re[b * NSYM_ + s];
        float yim = s_pim[sym] + sigma * noise_im[b * NSYM_ + s];
        #pragma unroll
        for (int j = 0; j < 4; ++j) {
            // pass 1: maxes for bit j (ascending p, same comparisons)
            float m0 = -1e30f, m1 = -1e30f;
            #pragma unroll
            for (int p = 0; p < 16; ++p) {
                float dre  = yre - s_pre[p];
                float dim_ = yim - s_pim[p];
                float lg   = -(dre * dre + dim_ * dim_) / no;
                if (((p >> (3 - j)) & 1) == 0) m0 = fmaxf(m0, lg);
                else                           m1 = fmaxf(m1, lg);
            }
            // pass 2: sums for bit j (identical fp sequence, ascending p)
            float sum0 = 0.0f, sum1 = 0.0f;
            #pragma unroll
            for (int p = 0; p < 16; ++p) {
                float dre  = yre - s_pre[p];
                float dim_ = yim - s_pim[p];
                float lg   = -(dre * dre + dim_ * dim_) / no;
                if (((p >> (3 - j)) & 1) == 0) sum0 += __expf(lg - m0);
                else                           sum1 += __expf(lg - m1);
            }
            float llr = (m0 + __logf(sum0)) - (m1 + __logf(sum1));
            s_mem[4 * s + j] = llr * LOG2E_;
        }
    }
    for (int idx = tid; idx < NIE_; idx += BS_) {
        int m = idx / 5, j = idx - m * 5;
        atomicAdd(&s_deg[edge_vn[m * ROW_ + j]], 1);
    }
    __syncthreads();

    // ---- degree histogram -> arithmetic segment bases (scan-free) ----
    for (int v = tid; v < K_; v += BS_) atomicAdd(&s_hist[s_deg[v] & 31], 1);
    __syncthreads();
    if (tid == 0) {
        int accS = 0, accB = 0;
        for (int d = 0; d < 32; ++d) {
            int c = s_hist[d];
            s_binStart[d] = accS;
            s_binBase[d]  = accB;
            s_hist[d]     = accS;        // reuse as sort cursor
            accS += c;
            accB += c * seg_stride(d);   // odd stride -> conflict-free
        }
    }
    __syncthreads();
    for (int v = tid; v < K_; v += BS_) {   // counting sort by degree
        int d    = s_deg[v];
        int slot = atomicAdd(&s_hist[d & 31], 1);
        int base = s_binBase[d] + (slot - s_binStart[d]) * seg_stride(d);
        s_perm[slot]  = v | (d << 16);
        s_offslot[v]  = base | (slot << 16);
    }
    __syncthreads();

    // ---- capture iteration-invariant state in registers ----
    int      pv[3];                      // slot -> VN id
    unsigned od[3];                      // base | deg<<16
    float    lr[3];                      // channel LLR_hat of owned VN
    #pragma unroll
    for (int k = 0; k < 3; ++k) {
        int s = tid + BS_ * k;
        if (s < K_) {
            int w = s_perm[s];
            int v = w & 0xFFFF;
            int d = w >> 16;
            int base = s_binBase[d] + (s - s_binStart[d]) * seg_stride(d);
            pv[k] = v;
            od[k] = (unsigned)base | ((unsigned)d << 16);
            lr[k] = s_mem[v];
        } else { pv[k] = 0; od[k] = 0; lr[k] = 0.0f; }
    }
    float    t5[3];
    unsigned vnp[3][5];                  // slot | pos<<16
    #pragma unroll
    for (int kk = 0; kk < 3; ++kk) {
        int m = tid + BS_ * kk;
        if (m < M_) {
            #pragma unroll
            for (int j = 0; j < 5; ++j) {
                int v = edge_vn[m * ROW_ + j];
                int r = atomicAdd(&s_cnt[v], 1);
                int w = s_offslot[v];
                vnp[kk][j]  = (unsigned)(w >> 16) | ((unsigned)((w & 0xFFFF) + r) << 16);
            }
            float lrP = s_mem[K_ + m];
            float av  = __builtin_amdgcn_fmed3f(fabsf(lrP), AVLO_, AVHI_);
            float e   = fexp2(-av);
            float tm  = (1.0f - e) * frcp(1.0f + e);
            t5[kk] = copysignf(tm, lrP);
        } else { t5[kk] = 0.0f; }
    }
    __syncthreads();
    // scratch fully consumed -> become the message array
    for (int i = tid; i < CAP_; i += BS_) s_mem[i] = 0.0f;
    __syncthreads();

    // ---- sum-product BP, flooding (bits domain) ----
    for (int it = 0; it < NITER_; ++it) {
        // Phase A: slot-indexed marginals; odd-stride sequential float
        // segments (R18 lesson: beats index-CSR gather)
        #pragma unroll
        for (int k = 0; k < 3; ++k) {
            int s = tid + BS_ * k;
            if (s < K_) {
                int base = (int)(od[k] & 0xFFFFu);
                int dg   = (int)(od[k] >> 16);
                float mg = lr[k];
                int d = 0;
                for (; d + 1 < dg; d += 2) {
                    mg += s_mem[base + d];
                    mg += s_mem[base + d + 1];
                }
                if (d < dg) mg += s_mem[base + d];
                s_marg[s] = mg;
            }
        }
        __syncthreads();
        // Phase B: CN update; old c2v re-read from LDS (single writer);
        // bare v_exp/v_log/v_rcp transcendentals
        #pragma unroll
        for (int kk = 0; kk < 3; ++kk) {
            int m = tid + BS_ * kk;
            if (m < M_) {
                float tj[5];
                #pragma unroll
                for (int j = 0; j < 5; ++j) {
                    unsigned w = vnp[kk][j];
                    float v2c = s_marg[w & 0xFFFFu] - s_mem[w >> 16];
                    float av  = __builtin_amdgcn_fmed3f(fabsf(v2c), AVLO_, AVHI_);
                    float e   = fexp2(-av);
                    float tm  = (1.0f - e) * frcp(1.0f + e);
                    tj[j] = copysignf(tm, v2c);
                }
                float qv[5];
                float pr = t5[kk];
                #pragma unroll
                for (int j = 0; j < 5; ++j) { qv[j] = pr; pr *= tj[j]; }
                float sf = 1.0f;
                #pragma unroll
                for (int j = 4; j >= 0; --j) { qv[j] *= sf; sf *= tj[j]; }
                #pragma unroll
                for (int j = 0; j < 5; ++j) {
                    float q = __builtin_amdgcn_fmed3f(qv[j], -QC_, QC_);
                    float r = flog2((1.0f + q) * frcp(1.0f - q));
                    s_mem[vnp[kk][j] >> 16] = r;
                }
            }
        }
        __syncthreads();
    }

    // ---- final marginal + hard decision on info VNs ----
    #pragma unroll
    for (int k = 0; k < 3; ++k) {
        int s = tid + BS_ * k;
        if (s < K_) {
            int base = (int)(od[k] & 0xFFFFu);
            int dg   = (int)(od[k] >> 16);
            float mg = lr[k];
            int d = 0;
            for (; d + 1 < dg; d += 2) {
                mg += s_mem[base + d];
                mg += s_mem[base + d + 1];
            }
            if (d < dg) mg += s_mem[base + d];
            out[(size_t)BATCH_ * K_ + b * K_ + pv[k]] = (mg < 0.0f) ? 1.0f : 0.0f;
        }
    }
}

extern "C" void kernel_launch(void* const* d_in, const int* in_sizes, int n_in,
                              void* d_out, int out_size, void* d_ws, size_t ws_size,
                              hipStream_t stream) {
    const int*   bits    = (const int*)  d_in[0];
    const int*   a_idx   = (const int*)  d_in[1];
    // d_in[2] = edge_cn (implicit: contiguous groups of 6) — unused
    const int*   edge_vn = (const int*)  d_in[3];
    const float* pre     = (const float*)d_in[4];
    const float* pim     = (const float*)d_in[5];
    const float* nre     = (const float*)d_in[6];
    const float* nim     = (const float*)d_in[7];
    const float* ebno    = (const float*)d_in[8];

    link_kernel<<<BATCH_, BS_, 0, stream>>>(bits, a_idx, pre, pim, nre, nim,
                                            ebno, edge_vn, (float*)d_out);
}